// Round 1
// baseline (21.548 us; speedup 1.0000x reference)
//
#include <hip/hip_runtime.h>

#define N_ENT 40943
#define DIM   128
#define BATCH 32
#define TILE  64      // entities per block
#define PAD   132     // 128 + 4 floats: breaks bank conflicts, keeps 16B align

__global__ __launch_bounds__(256) void transe_score_kernel(
    const int* __restrict__ heads,
    const int* __restrict__ rels,
    const float* __restrict__ ent_w,
    const float* __restrict__ rel_w,
    float* __restrict__ out)
{
    __shared__ float q[BATCH][DIM];   // 16 KB, read broadcast (no conflicts)
    __shared__ float t[TILE][PAD];    // 33 KB, padded stride

    const int tid = threadIdx.x;
    const int e0  = blockIdx.x * TILE;

    // --- stage q[b][:] = ent_w[heads[b]] + rel_w[rels[b]] ---
    // thread i -> batch b = i>>3, 16 floats starting at col (i&7)*16
    {
        const int b = tid >> 3;
        const int c = (tid & 7) * 16;
        const int h = heads[b];
        const int r = rels[b];
        const float4* eh = (const float4*)(ent_w + (size_t)h * DIM + c);
        const float4* rr = (const float4*)(rel_w + (size_t)r * DIM + c);
        float4* qd = (float4*)(&q[b][c]);
        #pragma unroll
        for (int k = 0; k < 4; ++k) {
            float4 a = eh[k], bb = rr[k];
            qd[k] = make_float4(a.x + bb.x, a.y + bb.y, a.z + bb.z, a.w + bb.w);
        }
    }

    // --- stage entity tile (coalesced global float4 -> padded LDS) ---
    {
        #pragma unroll
        for (int k = 0; k < 8; ++k) {
            int flat = (tid + k * 256) * 4;   // float index within 64x128 tile
            int r = flat >> 7;                // local row
            int c = flat & 127;
            int ge = e0 + r;
            if (ge >= N_ENT) ge = N_ENT - 1;  // clamp (guarded on store)
            float4 v = *(const float4*)(ent_w + (size_t)ge * DIM + c);
            *(float4*)(&t[r][c]) = v;
        }
    }
    __syncthreads();

    // --- compute: thread = (entity e_local, batch-group of 8) ---
    const int el = tid & 63;
    const int bg = (tid >> 6) * 8;

    float acc[8];
    #pragma unroll
    for (int j = 0; j < 8; ++j) acc[j] = 0.0f;

    #pragma unroll 8
    for (int d = 0; d < DIM; d += 4) {
        float4 tv = *(const float4*)(&t[el][d]);
        #pragma unroll
        for (int j = 0; j < 8; ++j) {
            float4 qv = *(const float4*)(&q[bg + j][d]);
            float dx = qv.x - tv.x;
            float dy = qv.y - tv.y;
            float dz = qv.z - tv.z;
            float dw = qv.w - tv.w;
            acc[j] = fmaf(dx, dx, acc[j]);
            acc[j] = fmaf(dy, dy, acc[j]);
            acc[j] = fmaf(dz, dz, acc[j]);
            acc[j] = fmaf(dw, dw, acc[j]);
        }
    }

    const int ge = e0 + el;
    if (ge < N_ENT) {
        #pragma unroll
        for (int j = 0; j < 8; ++j)
            out[(size_t)(bg + j) * N_ENT + ge] = acc[j];  // coalesced over el
    }
}

extern "C" void kernel_launch(void* const* d_in, const int* in_sizes, int n_in,
                              void* d_out, int out_size, void* d_ws, size_t ws_size,
                              hipStream_t stream) {
    const int*   heads = (const int*)d_in[0];
    const int*   rels  = (const int*)d_in[1];
    const float* ent_w = (const float*)d_in[2];
    const float* rel_w = (const float*)d_in[3];
    float* out = (float*)d_out;

    const int grid = (N_ENT + TILE - 1) / TILE;   // 640 blocks
    transe_score_kernel<<<grid, 256, 0, stream>>>(heads, rels, ent_w, rel_w, out);
}

// Round 2
// 18.249 us; speedup vs baseline: 1.1808x; 1.1808x over previous
//
#include <hip/hip_runtime.h>
#include <hip/hip_bf16.h>

#define N_ENT 40943
#define DIM   128
#define NB    32

typedef __attribute__((ext_vector_type(8))) short bfrag_t;
typedef __attribute__((ext_vector_type(4))) float f32x4_t;

__device__ inline short bf16_bits(float f) {
    __hip_bfloat16 h = __float2bfloat16(f);
    return *reinterpret_cast<short*>(&h);
}

// ws layout: [0, 8KB) = q as bf16[32][128]; then float qn[32]
__global__ __launch_bounds__(256) void prep_q(const int* __restrict__ heads,
                                              const int* __restrict__ rels,
                                              const float* __restrict__ ent_w,
                                              const float* __restrict__ rel_w,
                                              unsigned short* __restrict__ qbf,
                                              float* __restrict__ qn)
{
    const int t = threadIdx.x;           // 1 block x 256 threads
    const int b = t >> 3;                // batch 0..31 (8 threads per batch)
    const int c = (t & 7) * 16;          // this thread's 16-float chunk
    const int h = heads[b];
    const int r = rels[b];
    const float4* eh = (const float4*)(ent_w + (size_t)h * DIM + c);
    const float4* rr = (const float4*)(rel_w + (size_t)r * DIM + c);
    float part = 0.f;
    #pragma unroll
    for (int k = 0; k < 4; ++k) {
        float4 a = eh[k], bb = rr[k];
        float v0 = a.x + bb.x, v1 = a.y + bb.y, v2 = a.z + bb.z, v3 = a.w + bb.w;
        part = fmaf(v0, v0, fmaf(v1, v1, fmaf(v2, v2, fmaf(v3, v3, part))));
        short4 s;
        s.x = bf16_bits(v0); s.y = bf16_bits(v1);
        s.z = bf16_bits(v2); s.w = bf16_bits(v3);
        *(short4*)(qbf + b * DIM + c + 4 * k) = s;
    }
    // reduce the 8 per-batch partials (8-aligned lane groups within a wave)
    part += __shfl_down(part, 4);
    part += __shfl_down(part, 2);
    part += __shfl_down(part, 1);
    if ((t & 7) == 0) qn[b] = part;
}

// One wave per 16-entity tile; 32 batches via two 16x16x32 MFMA chains.
// No LDS, no __syncthreads.
__global__ __launch_bounds__(256) void transe_mfma(const float* __restrict__ ent_w,
                                                   const unsigned short* __restrict__ qbf,
                                                   const float* __restrict__ qn,
                                                   float* __restrict__ out)
{
    const int lane = threadIdx.x & 63;
    const int wid  = threadIdx.x >> 6;
    const int e0   = (blockIdx.x * 4 + wid) * 16;
    if (e0 >= N_ENT) return;             // whole-wave exit only (no barriers in kernel)

    const int er   = lane & 15;          // entity-in-tile == q row-in-tile
    const int kg   = lane >> 4;          // k-group 0..3 (8 contiguous k each)
    const int erow = e0 + er;
    const int eld  = erow < N_ENT ? erow : N_ENT - 1;   // clamp loads, mask stores

    // A fragments (q, bf16): lane holds rows {er, er+16}, k = 8*kg + 32*kt + j
    const unsigned short* qp = qbf + er * DIM + 8 * kg;
    bfrag_t a0[4], a1[4];
    #pragma unroll
    for (int kt = 0; kt < 4; ++kt) {
        a0[kt] = *(const bfrag_t*)(qp + 32 * kt);
        a1[kt] = *(const bfrag_t*)(qp + 16 * DIM + 32 * kt);
    }

    // B fragments: load t-row fp32 from global (used exactly once -> no LDS),
    // convert to bf16, and fold ||t||^2 partial from the same values.
    const float* tp = ent_w + (size_t)eld * DIM + 8 * kg;
    f32x4_t acc0 = {0.f, 0.f, 0.f, 0.f};
    f32x4_t acc1 = {0.f, 0.f, 0.f, 0.f};
    float tn = 0.f;
    #pragma unroll
    for (int kt = 0; kt < 4; ++kt) {
        f32x4_t t0 = *(const f32x4_t*)(tp + 32 * kt);
        f32x4_t t1 = *(const f32x4_t*)(tp + 32 * kt + 4);
        bfrag_t bf;
        #pragma unroll
        for (int j = 0; j < 4; ++j) {
            tn = fmaf(t0[j], t0[j], tn);
            tn = fmaf(t1[j], t1[j], tn);
            bf[j]     = bf16_bits(t0[j]);
            bf[j + 4] = bf16_bits(t1[j]);
        }
        acc0 = __builtin_amdgcn_mfma_f32_16x16x32_bf16(a0[kt], bf, acc0, 0, 0, 0);
        acc1 = __builtin_amdgcn_mfma_f32_16x16x32_bf16(a1[kt], bf, acc1, 0, 0, 0);
    }
    // lanes {er, er+16, er+32, er+48} cover complementary k-ranges of the same row
    tn += __shfl_xor(tn, 16);
    tn += __shfl_xor(tn, 32);

    if (erow < N_ENT) {
        #pragma unroll
        for (int r = 0; r < 4; ++r) {
            const int b0 = 4 * kg + r;   // C/D: row = 4*(lane>>4)+reg, col = lane&15
            out[(size_t)b0        * N_ENT + erow] = qn[b0]      + tn - 2.f * acc0[r];
            out[(size_t)(b0 + 16) * N_ENT + erow] = qn[b0 + 16] + tn - 2.f * acc1[r];
        }
    }
}

extern "C" void kernel_launch(void* const* d_in, const int* in_sizes, int n_in,
                              void* d_out, int out_size, void* d_ws, size_t ws_size,
                              hipStream_t stream) {
    const int*   heads = (const int*)d_in[0];
    const int*   rels  = (const int*)d_in[1];
    const float* ent_w = (const float*)d_in[2];
    const float* rel_w = (const float*)d_in[3];
    float* out = (float*)d_out;

    unsigned short* qbf = (unsigned short*)d_ws;
    float* qn = (float*)((char*)d_ws + (size_t)NB * DIM * sizeof(unsigned short));

    prep_q<<<1, 256, 0, stream>>>(heads, rels, ent_w, rel_w, qbf, qn);

    const int grid = (N_ENT + 63) / 64;   // 4 waves/block, 16 entities/wave -> 640 blocks
    transe_mfma<<<grid, 256, 0, stream>>>(ent_w, qbf, qn, out);
}

// Round 8
// 11.907 us; speedup vs baseline: 1.8097x; 1.5326x over previous
//
#include <hip/hip_runtime.h>
#include <hip/hip_bf16.h>

#define N_ENT 40943
#define DIM   128
#define NB    32
#define QPAD  136   // LDS row stride in bf16 elems (128+8): +4-bank shift/row, 16B aligned

typedef __attribute__((ext_vector_type(8))) short bfrag_t;
typedef __attribute__((ext_vector_type(4))) float f32x4_t;

__device__ inline short bf16_bits(float f) {
    __hip_bfloat16 h = __float2bfloat16(f);
    return *reinterpret_cast<short*>(&h);
}

// Single fused kernel: per-block q-prep (redundant, deterministic) + MFMA scoring.
// score[b,e] = ||q_b||^2 + ||t_e||^2 - 2 q_b . t_e
__global__ __launch_bounds__(256) void transe_fused(
    const int* __restrict__ heads,
    const int* __restrict__ rels,
    const float* __restrict__ ent_w,
    const float* __restrict__ rel_w,
    float* __restrict__ out)
{
    __shared__ unsigned short qbf[NB][QPAD];  // 8704 B, q rows as bf16
    __shared__ float qn[NB];                  // ||q_b||^2

    const int tid = threadIdx.x;

    // ---- prep: thread -> (batch b = tid>>3, 16-float chunk c = (tid&7)*16) ----
    {
        const int b = tid >> 3;
        const int c = (tid & 7) * 16;
        const int h = heads[b];
        const int r = rels[b];
        const float4* eh = (const float4*)(ent_w + (size_t)h * DIM + c);
        const float4* rr = (const float4*)(rel_w + (size_t)r * DIM + c);
        float part = 0.f;
        #pragma unroll
        for (int k = 0; k < 4; ++k) {
            float4 a = eh[k], bb = rr[k];
            float v0 = a.x + bb.x, v1 = a.y + bb.y, v2 = a.z + bb.z, v3 = a.w + bb.w;
            part = fmaf(v0, v0, fmaf(v1, v1, fmaf(v2, v2, fmaf(v3, v3, part))));
            short4 s;
            s.x = bf16_bits(v0); s.y = bf16_bits(v1);
            s.z = bf16_bits(v2); s.w = bf16_bits(v3);
            *(short4*)(&qbf[b][c + 4 * k]) = s;
        }
        // reduce 8 per-batch partials (8-aligned lane groups within a wave)
        part += __shfl_down(part, 4);
        part += __shfl_down(part, 2);
        part += __shfl_down(part, 1);
        if ((tid & 7) == 0) qn[b] = part;
    }
    __syncthreads();

    // ---- MFMA scoring: one wave per 16-entity tile ----
    const int lane = tid & 63;
    const int wid  = tid >> 6;
    const int e0   = (blockIdx.x * 4 + wid) * 16;

    const int er   = lane & 15;          // entity-in-tile == q row-in-tile
    const int kg   = lane >> 4;          // k-group 0..3 (8 contiguous k each)
    const int erow = e0 + er;
    const int eld  = erow < N_ENT ? erow : N_ENT - 1;   // clamp loads, mask stores

    // A fragments (q, bf16) from LDS: rows {er, er+16}, k = 8*kg + 32*kt + j
    bfrag_t a0[4], a1[4];
    #pragma unroll
    for (int kt = 0; kt < 4; ++kt) {
        a0[kt] = *(const bfrag_t*)(&qbf[er][8 * kg + 32 * kt]);
        a1[kt] = *(const bfrag_t*)(&qbf[er + 16][8 * kg + 32 * kt]);
    }

    // B fragments: t-row fp32 straight from global (each row used once -> no staging),
    // convert to bf16, fold ||t||^2 partial from the same values.
    const float* tp = ent_w + (size_t)eld * DIM + 8 * kg;
    f32x4_t acc0 = {0.f, 0.f, 0.f, 0.f};
    f32x4_t acc1 = {0.f, 0.f, 0.f, 0.f};
    float tn = 0.f;
    #pragma unroll
    for (int kt = 0; kt < 4; ++kt) {
        f32x4_t t0 = *(const f32x4_t*)(tp + 32 * kt);
        f32x4_t t1 = *(const f32x4_t*)(tp + 32 * kt + 4);
        bfrag_t bf;
        #pragma unroll
        for (int j = 0; j < 4; ++j) {
            tn = fmaf(t0[j], t0[j], tn);
            tn = fmaf(t1[j], t1[j], tn);
            bf[j]     = bf16_bits(t0[j]);
            bf[j + 4] = bf16_bits(t1[j]);
        }
        acc0 = __builtin_amdgcn_mfma_f32_16x16x32_bf16(a0[kt], bf, acc0, 0, 0, 0);
        acc1 = __builtin_amdgcn_mfma_f32_16x16x32_bf16(a1[kt], bf, acc1, 0, 0, 0);
    }
    // lanes {er, er+16, er+32, er+48} hold complementary k-ranges of the same t-row
    tn += __shfl_xor(tn, 16);
    tn += __shfl_xor(tn, 32);

    if (erow < N_ENT) {
        #pragma unroll
        for (int r = 0; r < 4; ++r) {
            const int b0 = 4 * kg + r;   // C/D: row = 4*(lane>>4)+reg, col = lane&15
            out[(size_t)b0        * N_ENT + erow] = qn[b0]      + tn - 2.f * acc0[r];
            out[(size_t)(b0 + 16) * N_ENT + erow] = qn[b0 + 16] + tn - 2.f * acc1[r];
        }
    }
}

extern "C" void kernel_launch(void* const* d_in, const int* in_sizes, int n_in,
                              void* d_out, int out_size, void* d_ws, size_t ws_size,
                              hipStream_t stream) {
    const int*   heads = (const int*)d_in[0];
    const int*   rels  = (const int*)d_in[1];
    const float* ent_w = (const float*)d_in[2];
    const float* rel_w = (const float*)d_in[3];
    float* out = (float*)d_out;

    const int grid = (N_ENT + 63) / 64;   // 4 waves/block, 16 entities/wave -> 640 blocks
    transe_fused<<<grid, 256, 0, stream>>>(heads, rels, ent_w, rel_w, out);
}